// Round 8
// baseline (55.552 us; speedup 1.0000x reference)
//
#include <hip/hip_runtime.h>
#include <math.h>

#define H 1024
#define T 4096
#define B 16

typedef float f4 __attribute__((ext_vector_type(4)));

// Kernel 1: v[b,h] = sum_d dec[d,b] * W[d,h]  (v = dec^T @ W, 16x1024)
// 512 blocks = 16 b x 32 htiles (32 h each); 2 blocks/CU -> 2 waves/SIMD.
__global__ void __launch_bounds__(256) proj_vec_kernel(
    const float* __restrict__ dec, const float* __restrict__ W,
    float* __restrict__ v)
{
    int b      = blockIdx.x >> 5;
    int htile  = blockIdx.x & 31;
    int h4     = threadIdx.x & 7;
    int dc     = threadIdx.x >> 3;
    int h4base = htile * 8;

    const f4* Wp = (const f4*)W;
    f4 acc = {0.f, 0.f, 0.f, 0.f};
    int d0 = dc * 32;
    #pragma unroll 8
    for (int i = 0; i < 32; ++i) {
        int d = d0 + i;
        float s = dec[d * B + b];
        f4 w = Wp[d * (H / 4) + h4base + h4];
        acc += s * w;
    }

    __shared__ f4 red[256];
    red[threadIdx.x] = acc;
    __syncthreads();
    #pragma unroll
    for (int s = 16; s > 0; s >>= 1) {
        if (dc < s) {
            f4 m = red[dc * 8 + h4] + red[(dc + s) * 8 + h4];
            red[dc * 8 + h4] = m;
        }
        __syncthreads();
    }
    if (dc == 0)
        ((f4*)(v + b * H))[h4base + h4] = red[h4];
}

// Kernel 2: scores[b,t] = dot(v[b,:], enc[t,b,:]).
// One wave per TWO rows adjacent in memory (same t, b0 and b0+1): wave
// streams 8 KiB contiguous with 8 independent NT loads in flight; block
// of 4 waves covers 32 KiB contiguous. f4 accumulators -> packed FMA.
// (R4's regression was 64-KiB-strided rows; these are contiguous.)
__global__ void __launch_bounds__(256) scores_kernel(
    const float* __restrict__ v, const float* __restrict__ enc,
    float* __restrict__ scores)
{
    int wave = (int)((blockIdx.x * 256u + threadIdx.x) >> 6);  // 0..32767
    int lane = threadIdx.x & 63;
    int r0 = wave * 2;            // linear row index = t*B + b, r0 even
    int t  = r0 >> 4;
    int b0 = r0 & 15;             // even, so b0+1 <= 15

    const f4* ep  = (const f4*)enc + (size_t)r0 * (H / 4) + lane;
    const f4* vp0 = (const f4*)(v + b0 * H) + lane;
    const f4* vp1 = vp0 + (H / 4);

    f4 e0[4], e1[4];
    #pragma unroll
    for (int i = 0; i < 4; ++i)
        e0[i] = __builtin_nontemporal_load(ep + i * 64);
    #pragma unroll
    for (int i = 0; i < 4; ++i)
        e1[i] = __builtin_nontemporal_load(ep + (H / 4) + i * 64);

    f4 a0 = {0.f, 0.f, 0.f, 0.f};
    f4 a1 = {0.f, 0.f, 0.f, 0.f};
    #pragma unroll
    for (int i = 0; i < 4; ++i) {
        a0 += e0[i] * vp0[i * 64];
        a1 += e1[i] * vp1[i * 64];
    }
    float s0 = (a0.x + a0.y) + (a0.z + a0.w);
    float s1 = (a1.x + a1.y) + (a1.z + a1.w);

    #pragma unroll
    for (int off = 32; off > 0; off >>= 1) {
        s0 += __shfl_down(s0, off);
        s1 += __shfl_down(s1, off);
    }
    if (lane == 0) {
        scores[(size_t)b0 * T + t] = s0;
        scores[(size_t)(b0 + 1) * T + t] = s1;
    }
}

// Kernel 3: row softmax, one block of 1024 threads (16 waves) per b.
__global__ void __launch_bounds__(1024) softmax_kernel(
    const float* __restrict__ scores, float* __restrict__ out)
{
    int b = blockIdx.x;
    int tid = threadIdx.x;
    int wid = tid >> 6;
    int lane = tid & 63;
    __shared__ float redm[16];
    __shared__ float reds[16];

    const f4* rp = (const f4*)(scores + (size_t)b * T);
    f4 x = rp[tid];

    float m = fmaxf(fmaxf(x.x, x.y), fmaxf(x.z, x.w));
    #pragma unroll
    for (int off = 32; off > 0; off >>= 1)
        m = fmaxf(m, __shfl_xor(m, off));
    if (lane == 0) redm[wid] = m;
    __syncthreads();
    m = redm[0];
    #pragma unroll
    for (int i = 1; i < 16; ++i) m = fmaxf(m, redm[i]);

    x.x = __expf(x.x - m);
    x.y = __expf(x.y - m);
    x.z = __expf(x.z - m);
    x.w = __expf(x.w - m);
    float s = x.x + x.y + x.z + x.w;
    #pragma unroll
    for (int off = 32; off > 0; off >>= 1)
        s += __shfl_xor(s, off);
    if (lane == 0) reds[wid] = s;
    __syncthreads();
    s = reds[0];
    #pragma unroll
    for (int i = 1; i < 16; ++i) s += reds[i];
    float inv = 1.f / s;

    f4 r = x * inv;
    __builtin_nontemporal_store(r, (f4*)(out + (size_t)b * T) + tid);
}

extern "C" void kernel_launch(void* const* d_in, const int* in_sizes, int n_in,
                              void* d_out, int out_size, void* d_ws, size_t ws_size,
                              hipStream_t stream)
{
    const float* dec = (const float*)d_in[0];   // [H, B]
    const float* enc = (const float*)d_in[1];   // [T, B, H]
    const float* W   = (const float*)d_in[2];   // [H, H]
    float* out = (float*)d_out;                 // [B, T]

    float* v      = (float*)d_ws;               // B*H floats
    float* scores = v + B * H;                  // B*T floats

    proj_vec_kernel<<<512, 256, 0, stream>>>(dec, W, v);
    scores_kernel<<<(T * B / 2) / 4, 256, 0, stream>>>(v, enc, scores);
    softmax_kernel<<<B, 1024, 0, stream>>>(scores, out);
}